// Round 1
// baseline (1935.618 us; speedup 1.0000x reference)
//
#include <hip/hip_runtime.h>
#include <math.h>

#define B_  64
#define S_  128
#define LW_ 20
#define CHAR_E_ 30
#define CHAR_C_ 30
#define WORD_E_ 300
#define H_  256
#define NC_ 25
#define F_  330
#define KP_ 336       // K padded to multiple of 16
#define G4_ 1024      // 4*H
#define NG_ 2048      // both directions' gates

__device__ __forceinline__ float sigmoidf_(float x){ return 1.0f/(1.0f+__expf(-x)); }
__device__ __forceinline__ float tanh_(float x){ return 1.0f - 2.0f/(1.0f+__expf(2.0f*x)); }

// ---------------- init: zero output scalar and cell state ----------------
__global__ void k_init(float* out, float* c){
    int i = blockIdx.x*256 + threadIdx.x;
    if(i == 0) *out = 0.f;
    if(i < 2*B_*H_) c[i] = 0.f;
}

// ---------------- pack w_ih (f then r) into (2048 x 336), zero-padded ----------------
__global__ void k_pack(const float* wf, const float* wr, float* wp){
    int i = blockIdx.x*256 + threadIdx.x;
    if(i >= NG_*KP_) return;
    int r = i / KP_, k = i % KP_;
    const float* src = (r < G4_) ? wf : wr;
    int rr = r & (G4_-1);
    wp[i] = (k < F_) ? src[(size_t)rr*F_ + k] : 0.f;
}

// ---------------- word embedding gather into feat cols [0,300), pad cols [330,336) ----------------
__global__ void k_wemb(const float* wt, const int* sent, float* feat){
    int idx = blockIdx.x*256 + threadIdx.x;
    if(idx >= B_*S_*76) return;
    int n = idx / 76, e4 = idx % 76;
    if(e4 < 75){
        float4 v = ((const float4*)(wt + (size_t)sent[n]*WORD_E_))[e4];
        ((float4*)(feat + (size_t)n*KP_))[e4] = v;
    } else {
        #pragma unroll
        for(int q=0;q<6;q++) feat[(size_t)n*KP_ + 330 + q] = 0.f;
    }
}

// ---------------- char conv + maxpool into feat cols [300,330) ----------------
// block = 256 threads handles 8 tokens
__global__ void k_charconv(const float* ct, const int* word, const float* cw,
                           const float* cb, float* feat){
    __shared__ __align__(16) float x[8][32][20];   // [tok][ic][t]
    int tok0 = blockIdx.x*8;
    for(int e = threadIdx.x; e < 8*32*20; e += 256){
        int t  = e % 20;
        int ic = (e/20) & 31;
        int tl = e / 640;
        int id = word[(size_t)(tok0+tl)*LW_ + t];
        float v = 0.f;
        if(ic < CHAR_E_ && id != 0) v = ct[(size_t)id*CHAR_E_ + ic];
        x[tl][ic][t] = v;
    }
    __syncthreads();
    int tid = threadIdx.x;
    if(tid < 240){
        int tl = tid/30, oc = tid%30;
        float acc[22];
        #pragma unroll
        for(int q=0;q<22;q++) acc[q] = 0.f;
        for(int ic=0; ic<CHAR_E_; ic++){
            float w0 = cw[(oc*CHAR_E_+ic)*3+0];
            float w1 = cw[(oc*CHAR_E_+ic)*3+1];
            float w2 = cw[(oc*CHAR_E_+ic)*3+2];
            const float* xr = &x[tl][ic][0];
            #pragma unroll
            for(int t4=0;t4<5;t4++){
                float4 v = ((const float4*)xr)[t4];
                int t0 = t4*4;
                // x[t'] contributes w0->out[t'+1], w1->out[t'], w2->out[t'-1]; acc[q] = out[q-1]
                acc[t0+2] += v.x*w0; acc[t0+1] += v.x*w1; acc[t0+0] += v.x*w2;
                acc[t0+3] += v.y*w0; acc[t0+2] += v.y*w1; acc[t0+1] += v.y*w2;
                acc[t0+4] += v.z*w0; acc[t0+3] += v.z*w1; acc[t0+2] += v.z*w2;
                acc[t0+5] += v.w*w0; acc[t0+4] += v.w*w1; acc[t0+3] += v.w*w2;
            }
        }
        float m = -1e30f;
        #pragma unroll
        for(int t=0;t<20;t++){ float v = acc[t+1]; m = fmaxf(m, v); }
        m += cb[oc];
        feat[(size_t)(tok0+tl)*KP_ + WORD_E_ + oc] = m;
    }
}

// ---------------- fp32 GEMM: gx[dir][s][b][row] = feat(8192x336) . wp(2048x336)^T + bias ----------------
#define BM 64
#define BN 64
#define BK 16
__global__ __launch_bounds__(256) void k_gemm(const float* A, const float* Bw,
                                              const float* bf, const float* br, float* gx){
    __shared__ __align__(16) float As[BK][BM];
    __shared__ __align__(16) float Bs[BK][BN];
    int m0 = blockIdx.x*BM, n0 = blockIdx.y*BN;
    int tid = threadIdx.x;
    int r = tid >> 2, cq = tid & 3;
    int tx = tid & 15, ty = tid >> 4;
    float acc[4][4];
    #pragma unroll
    for(int a=0;a<4;a++){
        #pragma unroll
        for(int b=0;b<4;b++) acc[a][b] = 0.f;
    }
    for(int k0 = 0; k0 < KP_; k0 += BK){
        float4 av = *(const float4*)(A  + (size_t)(m0 + r)*KP_ + k0 + cq*4);
        float4 bv = *(const float4*)(Bw + (size_t)(n0 + r)*KP_ + k0 + cq*4);
        __syncthreads();
        As[cq*4+0][r] = av.x; As[cq*4+1][r] = av.y; As[cq*4+2][r] = av.z; As[cq*4+3][r] = av.w;
        Bs[cq*4+0][r] = bv.x; Bs[cq*4+1][r] = bv.y; Bs[cq*4+2][r] = bv.z; Bs[cq*4+3][r] = bv.w;
        __syncthreads();
        #pragma unroll
        for(int kk=0; kk<BK; kk++){
            float4 a4 = *(const float4*)&As[kk][ty*4];
            float4 b4 = *(const float4*)&Bs[kk][tx*4];
            acc[0][0] += a4.x*b4.x; acc[0][1] += a4.x*b4.y; acc[0][2] += a4.x*b4.z; acc[0][3] += a4.x*b4.w;
            acc[1][0] += a4.y*b4.x; acc[1][1] += a4.y*b4.y; acc[1][2] += a4.y*b4.z; acc[1][3] += a4.y*b4.w;
            acc[2][0] += a4.z*b4.x; acc[2][1] += a4.z*b4.y; acc[2][2] += a4.z*b4.z; acc[2][3] += a4.z*b4.w;
            acc[3][0] += a4.w*b4.x; acc[3][1] += a4.w*b4.y; acc[3][2] += a4.w*b4.z; acc[3][3] += a4.w*b4.w;
        }
    }
    #pragma unroll
    for(int ii=0; ii<4; ii++){
        int m = m0 + ty*4 + ii;
        int b = m >> 7, s = m & 127;
        #pragma unroll
        for(int jj=0; jj<4; jj++){
            int n = n0 + tx*4 + jj;
            int dir = n >> 10, row = n & 1023;
            float bias = dir ? br[row] : bf[row];
            gx[(((size_t)dir*S_ + s)*B_ + b)*G4_ + row] = acc[ii][jj] + bias;
        }
    }
}

// ---------------- one LSTM step, both directions. grid (2, 32, 4), block 256 ----------------
// blockIdx: x=dir, y=jb (8 j-cols each), z=bc (16 batches each)
__global__ __launch_bounds__(256) void k_lstm_step(const float* whhf, const float* whhr,
                                                   const float* gx, float* hseq, float* c, int t){
    int dir = blockIdx.x;
    int jb  = blockIdx.y;
    int bc  = blockIdx.z;
    int s   = dir ? (S_-1-t) : t;
    const float* whh = dir ? whhr : whhf;
    __shared__ __align__(16) float hs[16][H_];     // 16 KB
    __shared__ float gbuf[4][8][16];
    int tid = threadIdx.x;
    if(t > 0){
        int sprev = dir ? (s+1) : (s-1);
        const float* hp = hseq + (((size_t)dir*S_ + sprev)*B_ + bc*16)*H_;
        for(int i = tid; i < 16*(H_/4); i += 256){
            int bl = i >> 6, k4 = i & 63;
            ((float4*)&hs[bl][0])[k4] = ((const float4*)(hp + (size_t)bl*H_))[k4];
        }
    } else {
        for(int i = tid; i < 16*H_; i += 256) ((float*)hs)[i] = 0.f;
    }
    __syncthreads();
    int g  = tid & 3;
    int jl = (tid >> 2) & 7;
    int bs = tid >> 5;           // 0..7, two batches each
    int jg = jb*8 + jl;
    int grow = g*H_ + jg;
    const float4* w4p = (const float4*)(whh + (size_t)grow*H_);
    int bl0 = bs*2, bl1 = bs*2+1;
    float acc0 = 0.f, acc1 = 0.f;
    #pragma unroll 4
    for(int k4 = 0; k4 < H_/4; k4++){
        float4 w4 = w4p[k4];
        float4 h0 = ((const float4*)&hs[bl0][0])[k4];
        float4 h1 = ((const float4*)&hs[bl1][0])[k4];
        acc0 += w4.x*h0.x + w4.y*h0.y + w4.z*h0.z + w4.w*h0.w;
        acc1 += w4.x*h1.x + w4.y*h1.y + w4.z*h1.z + w4.w*h1.w;
    }
    const float* gxp = gx + (((size_t)dir*S_ + s)*B_)*G4_;
    acc0 += gxp[(size_t)(bc*16+bl0)*G4_ + grow];
    acc1 += gxp[(size_t)(bc*16+bl1)*G4_ + grow];
    gbuf[g][jl][bl0] = acc0;
    gbuf[g][jl][bl1] = acc1;
    __syncthreads();
    if(tid < 128){
        int jl2 = tid >> 4, bl = tid & 15;
        int b = bc*16 + bl;
        int jg2 = jb*8 + jl2;
        float iv = gbuf[0][jl2][bl];
        float fv = gbuf[1][jl2][bl];
        float gv = gbuf[2][jl2][bl];
        float ov = gbuf[3][jl2][bl];
        size_t coff = ((size_t)dir*B_ + b)*H_ + jg2;
        float cold = (t==0) ? 0.f : c[coff];
        float cn = sigmoidf_(fv)*cold + sigmoidf_(iv)*tanh_(gv);
        float hn = sigmoidf_(ov)*tanh_(cn);
        c[coff] = cn;
        hseq[(((size_t)dir*S_ + s)*B_ + b)*H_ + jg2] = hn;
    }
}

// ---------------- emissions: em[s][b][nc] = [hf,hr] . lin_w[nc] + lin_b[nc] ----------------
__global__ void k_em(const float* hseq, const float* lw, const float* lb, float* em){
    int idx = blockIdx.x*256 + threadIdx.x;
    if(idx >= S_*B_*NC_) return;
    int nc = idx % NC_;
    int sb = idx / NC_;
    int b = sb % B_, s = sb / B_;
    const float4* hf = (const float4*)(hseq + (((size_t)0*S_ + s)*B_ + b)*H_);
    const float4* hr = (const float4*)(hseq + (((size_t)1*S_ + s)*B_ + b)*H_);
    const float4* w  = (const float4*)(lw + (size_t)nc*2*H_);
    float acc = lb[nc];
    #pragma unroll 8
    for(int k=0;k<H_/4;k++){ float4 a=hf[k], ww=w[k];     acc += a.x*ww.x + a.y*ww.y + a.z*ww.z + a.w*ww.w; }
    #pragma unroll 8
    for(int k=0;k<H_/4;k++){ float4 a=hr[k], ww=w[64+k];  acc += a.x*ww.x + a.y*ww.y + a.z*ww.z + a.w*ww.w; }
    em[idx] = acc;
}

// ---------------- CRF NLL: one block (64 threads) per batch; out += logZ - score ----------------
__global__ void k_crf(const float* em, const int* tag, const void* mask,
                      const float* st, const float* et, const float* tr, float* out){
    __shared__ float trs[NC_*NC_];
    __shared__ float alpha[2][NC_];
    __shared__ float score_sh;
    __shared__ int   len_sh;
    int b = blockIdx.x, tid = threadIdx.x;
    for(int i=tid;i<NC_*NC_;i+=64) trs[i]=tr[i];
    // mask layout detection: mask[0][0..] is always True (len >= 64)
    unsigned int first = *(const unsigned int*)mask;
    int ml;  // 0=int32, 1=uint8, 2=float32
    if(first == 1u) ml = 0;
    else if(first == 0x3F800000u) ml = 2;
    else ml = 1;
    __syncthreads();

    // gold path score
    float part = 0.f; int cnt = 0;
    for(int s = tid; s < S_; s += 64){
        float mkv;
        {
            int off = b*S_ + s;
            if(ml==0)      mkv = ((const int*)mask)[off] ? 1.f : 0.f;
            else if(ml==1) mkv = ((const unsigned char*)mask)[off] ? 1.f : 0.f;
            else           mkv = ((const float*)mask)[off];
        }
        cnt += (mkv != 0.f) ? 1 : 0;
        if(s == 0){
            int t0 = tag[b*S_];
            part += st[t0] + em[((size_t)0*B_ + b)*NC_ + t0];
        } else {
            int tp = tag[b*S_ + s-1], tc = tag[b*S_ + s];
            part += mkv * (trs[tp*NC_ + tc] + em[((size_t)s*B_ + b)*NC_ + tc]);
        }
    }
    for(int o=32;o>0;o>>=1){ part += __shfl_down(part, o); cnt += __shfl_down(cnt, o); }
    if(tid==0){ len_sh = cnt; score_sh = part; }
    __syncthreads();
    float score = 0.f;
    if(tid == 0){
        int last = len_sh - 1;
        score = score_sh + et[ tag[b*S_ + last] ];
    }

    // forward algorithm
    if(tid < NC_) alpha[0][tid] = st[tid] + em[((size_t)0*B_ + b)*NC_ + tid];
    __syncthreads();
    int cur = 0;
    for(int s=1;s<S_;s++){
        float nv = 0.f;
        if(tid < NC_){
            int j = tid;
            float m = -1e30f;
            #pragma unroll
            for(int i=0;i<NC_;i++){ float v = alpha[cur][i] + trs[i*NC_+j]; m = fmaxf(m, v); }
            float sum = 0.f;
            #pragma unroll
            for(int i=0;i<NC_;i++){ sum += __expf(alpha[cur][i] + trs[i*NC_+j] - m); }
            float nxt = m + __logf(sum) + em[((size_t)s*B_ + b)*NC_ + j];
            float mkv;
            {
                int off = b*S_ + s;
                if(ml==0)      mkv = ((const int*)mask)[off] ? 1.f : 0.f;
                else if(ml==1) mkv = ((const unsigned char*)mask)[off] ? 1.f : 0.f;
                else           mkv = ((const float*)mask)[off];
            }
            nv = (mkv != 0.f) ? nxt : alpha[cur][j];
        }
        __syncthreads();
        if(tid < NC_) alpha[cur^1][tid] = nv;
        __syncthreads();
        cur ^= 1;
    }
    float v = (tid < NC_) ? (alpha[cur][tid] + et[tid]) : -1e30f;
    float m = v;
    for(int o=32;o>0;o>>=1) m = fmaxf(m, __shfl_down(m, o));
    m = __shfl(m, 0);
    float e = (tid < NC_) ? __expf(v - m) : 0.f;
    for(int o=32;o>0;o>>=1) e += __shfl_down(e, o);
    if(tid == 0){
        float logZ = m + __logf(e);
        atomicAdd(out, logZ - score);
    }
}

extern "C" void kernel_launch(void* const* d_in, const int* in_sizes, int n_in,
                              void* d_out, int out_size, void* d_ws, size_t ws_size,
                              hipStream_t stream) {
    const float* word_table = (const float*)d_in[0];
    const float* char_table = (const float*)d_in[1];
    const float* conv_w     = (const float*)d_in[2];
    const float* conv_b     = (const float*)d_in[3];
    const float* w_ih_f     = (const float*)d_in[4];
    const float* w_hh_f     = (const float*)d_in[5];
    const float* b_f        = (const float*)d_in[6];
    const float* w_ih_r     = (const float*)d_in[7];
    const float* w_hh_r     = (const float*)d_in[8];
    const float* b_r        = (const float*)d_in[9];
    const float* lin_w      = (const float*)d_in[10];
    const float* lin_b      = (const float*)d_in[11];
    const float* start_t    = (const float*)d_in[12];
    const float* end_t      = (const float*)d_in[13];
    const float* trans      = (const float*)d_in[14];
    const int*   sent       = (const int*)d_in[15];
    const int*   word       = (const int*)d_in[16];
    const int*   tag        = (const int*)d_in[17];
    const void*  mask       = d_in[18];
    float* out = (float*)d_out;

    float* ws    = (float*)d_ws;
    float* feat  = ws;                                    // 8192*336      = 2,752,512
    float* wpack = feat  + (size_t)B_*S_*KP_;             // 2048*336      =   688,128
    float* gx    = wpack + (size_t)NG_*KP_;               // 2*128*64*1024 = 16,777,216
    float* hseq  = gx    + (size_t)2*S_*B_*G4_;           // 2*128*64*256  =  4,194,304
    float* cst   = hseq  + (size_t)2*S_*B_*H_;            // 2*64*256      =     32,768
    float* em    = cst   + (size_t)2*B_*H_;               // 128*64*25     =    204,800

    k_init<<<dim3(128), 256, 0, stream>>>(out, cst);
    k_pack<<<dim3((NG_*KP_+255)/256), 256, 0, stream>>>(w_ih_f, w_ih_r, wpack);
    k_wemb<<<dim3((B_*S_*76+255)/256), 256, 0, stream>>>(word_table, sent, feat);
    k_charconv<<<dim3(B_*S_/8), 256, 0, stream>>>(char_table, word, conv_w, conv_b, feat);
    k_gemm<<<dim3(B_*S_/BM, NG_/BN), 256, 0, stream>>>(feat, wpack, b_f, b_r, gx);
    for(int t=0;t<S_;t++)
        k_lstm_step<<<dim3(2,32,4), 256, 0, stream>>>(w_hh_f, w_hh_r, gx, hseq, cst, t);
    k_em<<<dim3((S_*B_*NC_+255)/256), 256, 0, stream>>>(hseq, lin_w, lin_b, em);
    k_crf<<<dim3(B_), 64, 0, stream>>>(em, tag, mask, start_t, end_t, trans, out);
}

// Round 2
// 1362.249 us; speedup vs baseline: 1.4209x; 1.4209x over previous
//
#include <hip/hip_runtime.h>
#include <math.h>

#define B_  64
#define S_  128
#define LW_ 20
#define CHAR_E_ 30
#define CHAR_C_ 30
#define WORD_E_ 300
#define H_  256
#define NC_ 25
#define F_  330
#define KP_ 336       // K padded to multiple of 16
#define G4_ 1024      // 4*H
#define NG_ 2048      // both directions' gates

typedef __attribute__((ext_vector_type(8))) short short8;
typedef __attribute__((ext_vector_type(4))) float floatx4;

__device__ __forceinline__ float sigmoidf_(float x){ return 1.0f/(1.0f+__expf(-x)); }
__device__ __forceinline__ float tanh_(float x){ return 1.0f - 2.0f/(1.0f+__expf(2.0f*x)); }

__device__ __forceinline__ unsigned short f2bf(float f){
    unsigned int u = __float_as_uint(f);
    u += 0x7FFFu + ((u>>16)&1u);
    return (unsigned short)(u>>16);
}
__device__ __forceinline__ short8 pack8(float4 a, float4 b){
    short8 r;
    r[0]=(short)f2bf(a.x); r[1]=(short)f2bf(a.y); r[2]=(short)f2bf(a.z); r[3]=(short)f2bf(a.w);
    r[4]=(short)f2bf(b.x); r[5]=(short)f2bf(b.y); r[6]=(short)f2bf(b.z); r[7]=(short)f2bf(b.w);
    return r;
}

// ---------------- init: zero output scalar and sync flags ----------------
__global__ void k_init(float* out, int* flags){
    int i = blockIdx.x*256 + threadIdx.x;
    if(i == 0) *out = 0.f;
    if(i < 8*32) flags[i] = 0;
}

// ---------------- pack w_ih (f then r) into (2048 x 336), zero-padded ----------------
__global__ void k_pack(const float* wf, const float* wr, float* wp){
    int i = blockIdx.x*256 + threadIdx.x;
    if(i >= NG_*KP_) return;
    int r = i / KP_, k = i % KP_;
    const float* src = (r < G4_) ? wf : wr;
    int rr = r & (G4_-1);
    wp[i] = (k < F_) ? src[(size_t)rr*F_ + k] : 0.f;
}

// ---------------- word embedding gather into feat cols [0,300), pad cols [330,336) ----------------
__global__ void k_wemb(const float* wt, const int* sent, float* feat){
    int idx = blockIdx.x*256 + threadIdx.x;
    if(idx >= B_*S_*76) return;
    int n = idx / 76, e4 = idx % 76;
    if(e4 < 75){
        float4 v = ((const float4*)(wt + (size_t)sent[n]*WORD_E_))[e4];
        ((float4*)(feat + (size_t)n*KP_))[e4] = v;
    } else {
        #pragma unroll
        for(int q=0;q<6;q++) feat[(size_t)n*KP_ + 330 + q] = 0.f;
    }
}

// ---------------- char conv + maxpool into feat cols [300,330) ----------------
__global__ void k_charconv(const float* ct, const int* word, const float* cw,
                           const float* cb, float* feat){
    __shared__ __align__(16) float x[8][32][20];   // [tok][ic][t]
    int tok0 = blockIdx.x*8;
    for(int e = threadIdx.x; e < 8*32*20; e += 256){
        int t  = e % 20;
        int ic = (e/20) & 31;
        int tl = e / 640;
        int id = word[(size_t)(tok0+tl)*LW_ + t];
        float v = 0.f;
        if(ic < CHAR_E_ && id != 0) v = ct[(size_t)id*CHAR_E_ + ic];
        x[tl][ic][t] = v;
    }
    __syncthreads();
    int tid = threadIdx.x;
    if(tid < 240){
        int tl = tid/30, oc = tid%30;
        float acc[22];
        #pragma unroll
        for(int q=0;q<22;q++) acc[q] = 0.f;
        for(int ic=0; ic<CHAR_E_; ic++){
            float w0 = cw[(oc*CHAR_E_+ic)*3+0];
            float w1 = cw[(oc*CHAR_E_+ic)*3+1];
            float w2 = cw[(oc*CHAR_E_+ic)*3+2];
            const float* xr = &x[tl][ic][0];
            #pragma unroll
            for(int t4=0;t4<5;t4++){
                float4 v = ((const float4*)xr)[t4];
                int t0 = t4*4;
                acc[t0+2] += v.x*w0; acc[t0+1] += v.x*w1; acc[t0+0] += v.x*w2;
                acc[t0+3] += v.y*w0; acc[t0+2] += v.y*w1; acc[t0+1] += v.y*w2;
                acc[t0+4] += v.z*w0; acc[t0+3] += v.z*w1; acc[t0+2] += v.z*w2;
                acc[t0+5] += v.w*w0; acc[t0+4] += v.w*w1; acc[t0+3] += v.w*w2;
            }
        }
        float m = -1e30f;
        #pragma unroll
        for(int t=0;t<20;t++){ float v = acc[t+1]; m = fmaxf(m, v); }
        m += cb[oc];
        feat[(size_t)(tok0+tl)*KP_ + WORD_E_ + oc] = m;
    }
}

// ---------------- fp32 GEMM: gx[dir][s][b][row] = feat(8192x336) . wp(2048x336)^T + bias ----------------
#define BM 64
#define BN 64
#define BK 16
__global__ __launch_bounds__(256) void k_gemm(const float* A, const float* Bw,
                                              const float* bf, const float* br, float* gx){
    __shared__ __align__(16) float As[BK][BM];
    __shared__ __align__(16) float Bs[BK][BN];
    int m0 = blockIdx.x*BM, n0 = blockIdx.y*BN;
    int tid = threadIdx.x;
    int r = tid >> 2, cq = tid & 3;
    int tx = tid & 15, ty = tid >> 4;
    float acc[4][4];
    #pragma unroll
    for(int a=0;a<4;a++){
        #pragma unroll
        for(int b=0;b<4;b++) acc[a][b] = 0.f;
    }
    for(int k0 = 0; k0 < KP_; k0 += BK){
        float4 av = *(const float4*)(A  + (size_t)(m0 + r)*KP_ + k0 + cq*4);
        float4 bv = *(const float4*)(Bw + (size_t)(n0 + r)*KP_ + k0 + cq*4);
        __syncthreads();
        As[cq*4+0][r] = av.x; As[cq*4+1][r] = av.y; As[cq*4+2][r] = av.z; As[cq*4+3][r] = av.w;
        Bs[cq*4+0][r] = bv.x; Bs[cq*4+1][r] = bv.y; Bs[cq*4+2][r] = bv.z; Bs[cq*4+3][r] = bv.w;
        __syncthreads();
        #pragma unroll
        for(int kk=0; kk<BK; kk++){
            float4 a4 = *(const float4*)&As[kk][ty*4];
            float4 b4 = *(const float4*)&Bs[kk][tx*4];
            acc[0][0] += a4.x*b4.x; acc[0][1] += a4.x*b4.y; acc[0][2] += a4.x*b4.z; acc[0][3] += a4.x*b4.w;
            acc[1][0] += a4.y*b4.x; acc[1][1] += a4.y*b4.y; acc[1][2] += a4.y*b4.z; acc[1][3] += a4.y*b4.w;
            acc[2][0] += a4.z*b4.x; acc[2][1] += a4.z*b4.y; acc[2][2] += a4.z*b4.z; acc[2][3] += a4.z*b4.w;
            acc[3][0] += a4.w*b4.x; acc[3][1] += a4.w*b4.y; acc[3][2] += a4.w*b4.z; acc[3][3] += a4.w*b4.w;
        }
    }
    #pragma unroll
    for(int ii=0; ii<4; ii++){
        int m = m0 + ty*4 + ii;
        int b = m >> 7, s = m & 127;
        #pragma unroll
        for(int jj=0; jj<4; jj++){
            int n = n0 + tx*4 + jj;
            int dir = n >> 10, row = n & 1023;
            float bias = dir ? br[row] : bf[row];
            gx[(((size_t)dir*S_ + s)*B_ + b)*G4_ + row] = acc[ii][jj] + bias;
        }
    }
}

// ---------------- persistent biLSTM: all 128 steps in one kernel ----------------
// 32 blocks x 256 threads. bid: dir = bid>>4, bg = (bid>>2)&3 (16 batches), jb = bid&3 (64 units).
// Weights (256 rows x 256 K, bf16) live in 128 VGPRs/lane as MFMA A-fragments.
// Per-step sync among the 4 jb-blocks of a (dir,bg) group via device-scope flag.
__global__ __launch_bounds__(256,1) void k_lstm_all(const float* whhf, const float* whhr,
        const float* gx, float* hseq, unsigned short* hstage, int* flags)
{
    int bid = blockIdx.x;
    int dir = bid >> 4;
    int bg  = (bid >> 2) & 3;
    int jb  = bid & 3;
    int tid = threadIdx.x;
    int lane = tid & 63;
    int wv   = tid >> 6;     // wave 0..3
    int q    = lane >> 4;    // quad 0..3
    int l16  = lane & 15;

    __shared__ __align__(16) unsigned short hlds[16*264];  // [batch][K], +8 pad: 2-way banks (free)

    const float* whh = dir ? whhr : whhf;

    // one-time: load my weight slice into registers as A-fragments
    // A-frag (16x16x32): m = lane&15 -> row g*256 + jb*64 + wv*16 + l16 ; k = q*8 + j
    short8 wreg[4][8];
    {
        int urow = jb*64 + wv*16 + l16;
        #pragma unroll
        for(int g=0; g<4; g++){
            const float* rp = whh + (size_t)(g*H_ + urow)*H_;
            #pragma unroll
            for(int kt=0; kt<8; kt++){
                int k0 = kt*32 + q*8;
                float4 x = *(const float4*)(rp + k0);
                float4 y = *(const float4*)(rp + k0 + 4);
                wreg[g][kt] = pack8(x, y);
            }
        }
    }

    int b_glob = bg*16 + l16;                 // batch for C cols / cell update
    int u0     = jb*64 + wv*16 + q*4;         // unit base for C rows (r=0..3)
    int* flag  = flags + (dir*4 + bg)*32;

    float cc0=0.f, cc1=0.f, cc2=0.f, cc3=0.f;  // cell state, register-resident

    for(int t=0; t<S_; t++){
        int s = dir ? (S_-1-t) : t;

        // prefetch gx before the spin so its latency hides under the wait
        floatx4 g0, g1, g2, g3;
        {
            const float* gp = gx + (((size_t)dir*S_ + s)*B_ + b_glob)*G4_ + u0;
            g0 = *(const floatx4*)(gp);
            g1 = *(const floatx4*)(gp + H_);
            g2 = *(const floatx4*)(gp + 2*H_);
            g3 = *(const floatx4*)(gp + 3*H_);
        }

        if(t > 0){
            if(tid == 0){
                while(__hip_atomic_load(flag, __ATOMIC_ACQUIRE, __HIP_MEMORY_SCOPE_AGENT) < 4*t){ }
            }
            __syncthreads();
            const unsigned short* hsrc = hstage
                + ((size_t)(((t&1)^1)*2 + dir)*4 + bg)*16*256;
            for(int c = tid; c < 512; c += 256){       // 16 batches x 32 chunks of 16B
                int bt = c >> 5, off = (c & 31)*8;
                uint4 v = *(const uint4*)(hsrc + bt*256 + off);
                *(uint4*)&hlds[bt*264 + off] = v;
            }
        } else {
            for(int i = tid; i < 16*264; i += 256) hlds[i] = 0;
        }
        __syncthreads();

        // gates = W @ h : D(256x16) accumulated as 4 gate-tiles per wave
        floatx4 a0={0.f,0.f,0.f,0.f}, a1=a0, a2=a0, a3=a0;
        #pragma unroll
        for(int kt=0; kt<8; kt++){
            short8 bf = *(const short8*)&hlds[l16*264 + kt*32 + q*8];
            a0 = __builtin_amdgcn_mfma_f32_16x16x32_bf16(wreg[0][kt], bf, a0, 0,0,0);
            a1 = __builtin_amdgcn_mfma_f32_16x16x32_bf16(wreg[1][kt], bf, a1, 0,0,0);
            a2 = __builtin_amdgcn_mfma_f32_16x16x32_bf16(wreg[2][kt], bf, a2, 0,0,0);
            a3 = __builtin_amdgcn_mfma_f32_16x16x32_bf16(wreg[3][kt], bf, a3, 0,0,0);
        }

        // cell update (C layout: col=l16=batch, row=q*4+r -> unit u0+r)
        float hv0, hv1, hv2, hv3;
        {
            float iv, fv, gv, ov, cn;
            iv=a0[0]+g0[0]; fv=a1[0]+g1[0]; gv=a2[0]+g2[0]; ov=a3[0]+g3[0];
            cn = sigmoidf_(fv)*cc0 + sigmoidf_(iv)*tanh_(gv); cc0=cn; hv0 = sigmoidf_(ov)*tanh_(cn);
            iv=a0[1]+g0[1]; fv=a1[1]+g1[1]; gv=a2[1]+g2[1]; ov=a3[1]+g3[1];
            cn = sigmoidf_(fv)*cc1 + sigmoidf_(iv)*tanh_(gv); cc1=cn; hv1 = sigmoidf_(ov)*tanh_(cn);
            iv=a0[2]+g0[2]; fv=a1[2]+g1[2]; gv=a2[2]+g2[2]; ov=a3[2]+g3[2];
            cn = sigmoidf_(fv)*cc2 + sigmoidf_(iv)*tanh_(gv); cc2=cn; hv2 = sigmoidf_(ov)*tanh_(cn);
            iv=a0[3]+g0[3]; fv=a1[3]+g1[3]; gv=a2[3]+g2[3]; ov=a3[3]+g3[3];
            cn = sigmoidf_(fv)*cc3 + sigmoidf_(iv)*tanh_(gv); cc3=cn; hv3 = sigmoidf_(ov)*tanh_(cn);
        }

        // hseq fp32 (for emissions)
        *(float4*)(hseq + (((size_t)dir*S_ + s)*B_ + b_glob)*H_ + u0) = make_float4(hv0,hv1,hv2,hv3);
        // hstage bf16 (for peers' next-step B-fragments), double-buffered by t&1
        unsigned long long hp = (unsigned long long)f2bf(hv0)
                              | ((unsigned long long)f2bf(hv1) << 16)
                              | ((unsigned long long)f2bf(hv2) << 32)
                              | ((unsigned long long)f2bf(hv3) << 48);
        *(unsigned long long*)(hstage + ((size_t)((t&1)*2 + dir)*4 + bg)*16*256 + l16*256 + u0) = hp;

        __threadfence();          // release stores to agent scope
        __syncthreads();
        if(tid == 0) __hip_atomic_fetch_add(flag, 1, __ATOMIC_RELEASE, __HIP_MEMORY_SCOPE_AGENT);
    }
}

// ---------------- emissions: em[s][b][nc] = [hf,hr] . lin_w[nc] + lin_b[nc] ----------------
__global__ void k_em(const float* hseq, const float* lw, const float* lb, float* em){
    int idx = blockIdx.x*256 + threadIdx.x;
    if(idx >= S_*B_*NC_) return;
    int nc = idx % NC_;
    int sb = idx / NC_;
    int b = sb % B_, s = sb / B_;
    const float4* hf = (const float4*)(hseq + (((size_t)0*S_ + s)*B_ + b)*H_);
    const float4* hr = (const float4*)(hseq + (((size_t)1*S_ + s)*B_ + b)*H_);
    const float4* w  = (const float4*)(lw + (size_t)nc*2*H_);
    float acc = lb[nc];
    #pragma unroll 8
    for(int k=0;k<H_/4;k++){ float4 a=hf[k], ww=w[k];     acc += a.x*ww.x + a.y*ww.y + a.z*ww.z + a.w*ww.w; }
    #pragma unroll 8
    for(int k=0;k<H_/4;k++){ float4 a=hr[k], ww=w[64+k];  acc += a.x*ww.x + a.y*ww.y + a.z*ww.z + a.w*ww.w; }
    em[idx] = acc;
}

// ---------------- CRF NLL: one block (64 threads) per batch; out += logZ - score ----------------
__global__ void k_crf(const float* em, const int* tag, const void* mask,
                      const float* st, const float* et, const float* tr, float* out){
    __shared__ float trs[NC_*NC_];
    __shared__ float alpha[2][NC_];
    __shared__ float score_sh;
    __shared__ int   len_sh;
    int b = blockIdx.x, tid = threadIdx.x;
    for(int i=tid;i<NC_*NC_;i+=64) trs[i]=tr[i];
    unsigned int first = *(const unsigned int*)mask;
    int ml;  // 0=int32, 1=uint8, 2=float32
    if(first == 1u) ml = 0;
    else if(first == 0x3F800000u) ml = 2;
    else ml = 1;
    __syncthreads();

    float part = 0.f; int cnt = 0;
    for(int s = tid; s < S_; s += 64){
        float mkv;
        {
            int off = b*S_ + s;
            if(ml==0)      mkv = ((const int*)mask)[off] ? 1.f : 0.f;
            else if(ml==1) mkv = ((const unsigned char*)mask)[off] ? 1.f : 0.f;
            else           mkv = ((const float*)mask)[off];
        }
        cnt += (mkv != 0.f) ? 1 : 0;
        if(s == 0){
            int t0 = tag[b*S_];
            part += st[t0] + em[((size_t)0*B_ + b)*NC_ + t0];
        } else {
            int tp = tag[b*S_ + s-1], tc = tag[b*S_ + s];
            part += mkv * (trs[tp*NC_ + tc] + em[((size_t)s*B_ + b)*NC_ + tc]);
        }
    }
    for(int o=32;o>0;o>>=1){ part += __shfl_down(part, o); cnt += __shfl_down(cnt, o); }
    if(tid==0){ len_sh = cnt; score_sh = part; }
    __syncthreads();
    float score = 0.f;
    if(tid == 0){
        int last = len_sh - 1;
        score = score_sh + et[ tag[b*S_ + last] ];
    }

    if(tid < NC_) alpha[0][tid] = st[tid] + em[((size_t)0*B_ + b)*NC_ + tid];
    __syncthreads();
    int cur = 0;
    for(int s=1;s<S_;s++){
        float nv = 0.f;
        if(tid < NC_){
            int j = tid;
            float m = -1e30f;
            #pragma unroll
            for(int i=0;i<NC_;i++){ float v = alpha[cur][i] + trs[i*NC_+j]; m = fmaxf(m, v); }
            float sum = 0.f;
            #pragma unroll
            for(int i=0;i<NC_;i++){ sum += __expf(alpha[cur][i] + trs[i*NC_+j] - m); }
            float nxt = m + __logf(sum) + em[((size_t)s*B_ + b)*NC_ + j];
            float mkv;
            {
                int off = b*S_ + s;
                if(ml==0)      mkv = ((const int*)mask)[off] ? 1.f : 0.f;
                else if(ml==1) mkv = ((const unsigned char*)mask)[off] ? 1.f : 0.f;
                else           mkv = ((const float*)mask)[off];
            }
            nv = (mkv != 0.f) ? nxt : alpha[cur][j];
        }
        __syncthreads();
        if(tid < NC_) alpha[cur^1][tid] = nv;
        __syncthreads();
        cur ^= 1;
    }
    float v = (tid < NC_) ? (alpha[cur][tid] + et[tid]) : -1e30f;
    float m = v;
    for(int o=32;o>0;o>>=1) m = fmaxf(m, __shfl_down(m, o));
    m = __shfl(m, 0);
    float e = (tid < NC_) ? __expf(v - m) : 0.f;
    for(int o=32;o>0;o>>=1) e += __shfl_down(e, o);
    if(tid == 0){
        float logZ = m + __logf(e);
        atomicAdd(out, logZ - score);
    }
}

extern "C" void kernel_launch(void* const* d_in, const int* in_sizes, int n_in,
                              void* d_out, int out_size, void* d_ws, size_t ws_size,
                              hipStream_t stream) {
    const float* word_table = (const float*)d_in[0];
    const float* char_table = (const float*)d_in[1];
    const float* conv_w     = (const float*)d_in[2];
    const float* conv_b     = (const float*)d_in[3];
    const float* w_ih_f     = (const float*)d_in[4];
    const float* w_hh_f     = (const float*)d_in[5];
    const float* b_f        = (const float*)d_in[6];
    const float* w_ih_r     = (const float*)d_in[7];
    const float* w_hh_r     = (const float*)d_in[8];
    const float* b_r        = (const float*)d_in[9];
    const float* lin_w      = (const float*)d_in[10];
    const float* lin_b      = (const float*)d_in[11];
    const float* start_t    = (const float*)d_in[12];
    const float* end_t      = (const float*)d_in[13];
    const float* trans      = (const float*)d_in[14];
    const int*   sent       = (const int*)d_in[15];
    const int*   word       = (const int*)d_in[16];
    const int*   tag        = (const int*)d_in[17];
    const void*  mask       = d_in[18];
    float* out = (float*)d_out;

    float* ws    = (float*)d_ws;
    float* feat  = ws;                                    // 8192*336      = 2,752,512
    float* wpack = feat  + (size_t)B_*S_*KP_;             // 2048*336      =   688,128
    float* gx    = wpack + (size_t)NG_*KP_;               // 2*128*64*1024 = 16,777,216
    float* hseq  = gx    + (size_t)2*S_*B_*G4_;           // 2*128*64*256  =  4,194,304
    float* em    = hseq  + (size_t)2*S_*B_*H_;            // 128*64*25     =    204,800
    unsigned short* hstage = (unsigned short*)(em + (size_t)S_*B_*NC_);  // 2*2*4*16*256 u16 = 131072 B
    int*   flags = (int*)(hstage + (size_t)2*2*4*16*256); // 8*32 ints

    k_init<<<dim3(1), 256, 0, stream>>>(out, flags);
    k_pack<<<dim3((NG_*KP_+255)/256), 256, 0, stream>>>(w_ih_f, w_ih_r, wpack);
    k_wemb<<<dim3((B_*S_*76+255)/256), 256, 0, stream>>>(word_table, sent, feat);
    k_charconv<<<dim3(B_*S_/8), 256, 0, stream>>>(char_table, word, conv_w, conv_b, feat);
    k_gemm<<<dim3(B_*S_/BM, NG_/BN), 256, 0, stream>>>(feat, wpack, b_f, b_r, gx);
    k_lstm_all<<<dim3(32), 256, 0, stream>>>(w_hh_f, w_hh_r, gx, hseq, hstage, flags);
    k_em<<<dim3((S_*B_*NC_+255)/256), 256, 0, stream>>>(hseq, lin_w, lin_b, em);
    k_crf<<<dim3(B_), 64, 0, stream>>>(em, tag, mask, start_t, end_t, trans, out);
}

// Round 3
// 906.808 us; speedup vs baseline: 2.1345x; 1.5022x over previous
//
#include <hip/hip_runtime.h>
#include <math.h>

#define B_  64
#define S_  128
#define LW_ 20
#define CHAR_E_ 30
#define CHAR_C_ 30
#define WORD_E_ 300
#define H_  256
#define NC_ 25
#define F_  330
#define KP_ 336       // K padded to multiple of 16
#define G4_ 1024      // 4*H
#define NG_ 2048      // both directions' gates

typedef __attribute__((ext_vector_type(8))) short short8;
typedef __attribute__((ext_vector_type(4))) float floatx4;

__device__ __forceinline__ float sigmoidf_(float x){ return 1.0f/(1.0f+__expf(-x)); }
__device__ __forceinline__ float tanh_(float x){ return 1.0f - 2.0f/(1.0f+__expf(2.0f*x)); }

__device__ __forceinline__ unsigned int f2bf(float f){
    unsigned int u = __float_as_uint(f);
    u += 0x7FFFu + ((u>>16)&1u);
    return (u>>16) & 0xFFFFu;
}
__device__ __forceinline__ short8 pack8(float4 a, float4 b){
    short8 r;
    r[0]=(short)f2bf(a.x); r[1]=(short)f2bf(a.y); r[2]=(short)f2bf(a.z); r[3]=(short)f2bf(a.w);
    r[4]=(short)f2bf(b.x); r[5]=(short)f2bf(b.y); r[6]=(short)f2bf(b.z); r[7]=(short)f2bf(b.w);
    return r;
}

// ---------------- init: zero output scalar ----------------
__global__ void k_init(float* out){
    if(blockIdx.x==0 && threadIdx.x==0) *out = 0.f;
}

// ---------------- pack w_ih (f then r) into (2048 x 336), zero-padded ----------------
__global__ void k_pack(const float* wf, const float* wr, float* wp){
    int i = blockIdx.x*256 + threadIdx.x;
    if(i >= NG_*KP_) return;
    int r = i / KP_, k = i % KP_;
    const float* src = (r < G4_) ? wf : wr;
    int rr = r & (G4_-1);
    wp[i] = (k < F_) ? src[(size_t)rr*F_ + k] : 0.f;
}

// ---------------- word embedding gather into feat cols [0,300), pad cols [330,336) ----------------
__global__ void k_wemb(const float* wt, const int* sent, float* feat){
    int idx = blockIdx.x*256 + threadIdx.x;
    if(idx >= B_*S_*76) return;
    int n = idx / 76, e4 = idx % 76;
    if(e4 < 75){
        float4 v = ((const float4*)(wt + (size_t)sent[n]*WORD_E_))[e4];
        ((float4*)(feat + (size_t)n*KP_))[e4] = v;
    } else {
        #pragma unroll
        for(int q=0;q<6;q++) feat[(size_t)n*KP_ + 330 + q] = 0.f;
    }
}

// ---------------- char conv + maxpool into feat cols [300,330) ----------------
__global__ void k_charconv(const float* ct, const int* word, const float* cw,
                           const float* cb, float* feat){
    __shared__ __align__(16) float x[8][32][20];   // [tok][ic][t]
    int tok0 = blockIdx.x*8;
    for(int e = threadIdx.x; e < 8*32*20; e += 256){
        int t  = e % 20;
        int ic = (e/20) & 31;
        int tl = e / 640;
        int id = word[(size_t)(tok0+tl)*LW_ + t];
        float v = 0.f;
        if(ic < CHAR_E_ && id != 0) v = ct[(size_t)id*CHAR_E_ + ic];
        x[tl][ic][t] = v;
    }
    __syncthreads();
    int tid = threadIdx.x;
    if(tid < 240){
        int tl = tid/30, oc = tid%30;
        float acc[22];
        #pragma unroll
        for(int q=0;q<22;q++) acc[q] = 0.f;
        for(int ic=0; ic<CHAR_E_; ic++){
            float w0 = cw[(oc*CHAR_E_+ic)*3+0];
            float w1 = cw[(oc*CHAR_E_+ic)*3+1];
            float w2 = cw[(oc*CHAR_E_+ic)*3+2];
            const float* xr = &x[tl][ic][0];
            #pragma unroll
            for(int t4=0;t4<5;t4++){
                float4 v = ((const float4*)xr)[t4];
                int t0 = t4*4;
                acc[t0+2] += v.x*w0; acc[t0+1] += v.x*w1; acc[t0+0] += v.x*w2;
                acc[t0+3] += v.y*w0; acc[t0+2] += v.y*w1; acc[t0+1] += v.y*w2;
                acc[t0+4] += v.z*w0; acc[t0+3] += v.z*w1; acc[t0+2] += v.z*w2;
                acc[t0+5] += v.w*w0; acc[t0+4] += v.w*w1; acc[t0+3] += v.w*w2;
            }
        }
        float m = -1e30f;
        #pragma unroll
        for(int t=0;t<20;t++){ float v = acc[t+1]; m = fmaxf(m, v); }
        m += cb[oc];
        feat[(size_t)(tok0+tl)*KP_ + WORD_E_ + oc] = m;
    }
}

// ---------------- fp32 GEMM: gx[dir][s][b][row] = feat(8192x336) . wp(2048x336)^T + bias ----------------
#define BM 64
#define BN 64
#define BK 16
__global__ __launch_bounds__(256) void k_gemm(const float* A, const float* Bw,
                                              const float* bf, const float* br, float* gx){
    __shared__ __align__(16) float As[BK][BM];
    __shared__ __align__(16) float Bs[BK][BN];
    int m0 = blockIdx.x*BM, n0 = blockIdx.y*BN;
    int tid = threadIdx.x;
    int r = tid >> 2, cq = tid & 3;
    int tx = tid & 15, ty = tid >> 4;
    float acc[4][4];
    #pragma unroll
    for(int a=0;a<4;a++){
        #pragma unroll
        for(int b=0;b<4;b++) acc[a][b] = 0.f;
    }
    for(int k0 = 0; k0 < KP_; k0 += BK){
        float4 av = *(const float4*)(A  + (size_t)(m0 + r)*KP_ + k0 + cq*4);
        float4 bv = *(const float4*)(Bw + (size_t)(n0 + r)*KP_ + k0 + cq*4);
        __syncthreads();
        As[cq*4+0][r] = av.x; As[cq*4+1][r] = av.y; As[cq*4+2][r] = av.z; As[cq*4+3][r] = av.w;
        Bs[cq*4+0][r] = bv.x; Bs[cq*4+1][r] = bv.y; Bs[cq*4+2][r] = bv.z; Bs[cq*4+3][r] = bv.w;
        __syncthreads();
        #pragma unroll
        for(int kk=0; kk<BK; kk++){
            float4 a4 = *(const float4*)&As[kk][ty*4];
            float4 b4 = *(const float4*)&Bs[kk][tx*4];
            acc[0][0] += a4.x*b4.x; acc[0][1] += a4.x*b4.y; acc[0][2] += a4.x*b4.z; acc[0][3] += a4.x*b4.w;
            acc[1][0] += a4.y*b4.x; acc[1][1] += a4.y*b4.y; acc[1][2] += a4.y*b4.z; acc[1][3] += a4.y*b4.w;
            acc[2][0] += a4.z*b4.x; acc[2][1] += a4.z*b4.y; acc[2][2] += a4.z*b4.z; acc[2][3] += a4.z*b4.w;
            acc[3][0] += a4.w*b4.x; acc[3][1] += a4.w*b4.y; acc[3][2] += a4.w*b4.z; acc[3][3] += a4.w*b4.w;
        }
    }
    #pragma unroll
    for(int ii=0; ii<4; ii++){
        int m = m0 + ty*4 + ii;
        int b = m >> 7, s = m & 127;
        #pragma unroll
        for(int jj=0; jj<4; jj++){
            int n = n0 + tx*4 + jj;
            int dir = n >> 10, row = n & 1023;
            float bias = dir ? br[row] : bf[row];
            gx[(((size_t)dir*S_ + s)*B_ + b)*G4_ + row] = acc[ii][jj] + bias;
        }
    }
}

// ---------------- persistent biLSTM: all 128 steps in one kernel ----------------
// 32 blocks x 256 threads. bid: dir = bid>>4, bg = (bid>>2)&3 (16 batches), jb = bid&3 (64 units).
// Weights (256 gate-rows x 256 K, bf16) live in 128 VGPRs/lane as MFMA A-fragments.
// h exchange among the 4 jb-blocks of a (dir,bg) group via RELAXED agent-scope 64-bit
// atomics carrying (tag<<32 | 2x bf16) — self-validating words, no fences, no L2 flushes.
// Double-buffered by t&1; block barrier between read-phase and publish-phase makes it safe.
__global__ __launch_bounds__(256,1) void k_lstm_all(const float* whhf, const float* whhr,
        const float* gx, float* hseq, unsigned long long* hstage64)
{
    int bid = blockIdx.x;
    int dir = bid >> 4;
    int bg  = (bid >> 2) & 3;
    int jb  = bid & 3;
    int tid = threadIdx.x;
    int lane = tid & 63;
    int wv   = tid >> 6;     // wave 0..3
    int q    = lane >> 4;    // quad 0..3
    int l16  = lane & 15;

    __shared__ __align__(16) unsigned short hlds[16*264];  // [batch][unit], +8 pad

    const float* whh = dir ? whhr : whhf;

    // one-time: load my weight slice into registers as A-fragments
    // A-frag (16x16x32): m = lane&15 -> row g*256 + jb*64 + wv*16 + l16 ; k = q*8 + j
    short8 wreg[4][8];
    {
        int urow = jb*64 + wv*16 + l16;
        #pragma unroll
        for(int g=0; g<4; g++){
            const float* rp = whh + (size_t)(g*H_ + urow)*H_;
            #pragma unroll
            for(int kt=0; kt<8; kt++){
                int k0 = kt*32 + q*8;
                float4 x = *(const float4*)(rp + k0);
                float4 y = *(const float4*)(rp + k0 + 4);
                wreg[g][kt] = pack8(x, y);
            }
        }
    }

    int b_glob = bg*16 + l16;                 // batch for C cols / cell update
    int u0     = jb*64 + wv*16 + q*4;         // unit base for C rows (r=0..3)
    int ul0    = wv*8 + q*2;                  // local unit-pair index (within jb), 0..31

    // group slot base (1 dir x 1 bg): 4 jb x 512 words
    unsigned long long* grp0 = hstage64 + ((size_t)dir*4 + bg)*4*512;            // buf 0
    unsigned long long* grp1 = hstage64 + (size_t)2*2*4*4*512/2 /*=buf stride*/  // see below
                              + ((size_t)dir*4 + bg)*4*512;
    // buf stride = 2 dir * 4 bg * 4 jb * 512 = 16384 words

    float cc0=0.f, cc1=0.f, cc2=0.f, cc3=0.f;  // cell state, register-resident

    // zero LDS once (t=0 uses h = 0)
    for(int i = tid; i < 16*264; i += 256) hlds[i] = 0;

    for(int t=0; t<S_; t++){
        int s = dir ? (S_-1-t) : t;

        // prefetch gx before the exchange so its latency hides under the wait
        floatx4 g0, g1, g2, g3;
        {
            const float* gp = gx + (((size_t)dir*S_ + s)*B_ + b_glob)*G4_ + u0;
            g0 = *(const floatx4*)(gp);
            g1 = *(const floatx4*)(gp + H_);
            g2 = *(const floatx4*)(gp + 2*H_);
            g3 = *(const floatx4*)(gp + 3*H_);
        }

        if(t > 0){
            int tprev = t-1;
            unsigned long long* base = ((tprev & 1) ? grp1 : grp0);
            #pragma unroll
            for(int j=0;j<6;j++){
                int flat = tid*6 + j;
                int pi = flat >> 9;              // 0..2
                int w  = flat & 511;
                int jp = (jb + 1 + pi) & 3;      // peer block
                unsigned long long* p = base + (size_t)jp*512 + w;
                unsigned long long v;
                do { v = __hip_atomic_load(p, __ATOMIC_RELAXED, __HIP_MEMORY_SCOPE_AGENT); }
                while ((unsigned)(v>>32) != (unsigned)tprev);
                int ul = w >> 4, bt = w & 15;
                *(unsigned int*)((char*)hlds + ((size_t)bt*264 + jp*64 + ul*2)*2) = (unsigned int)v;
            }
        }
        __syncthreads();

        // gates = W @ h : D(256x16) accumulated as 4 gate-tiles per wave
        floatx4 a0={0.f,0.f,0.f,0.f}, a1=a0, a2=a0, a3=a0;
        #pragma unroll
        for(int kt=0; kt<8; kt++){
            short8 bfr = *(const short8*)&hlds[l16*264 + kt*32 + q*8];
            a0 = __builtin_amdgcn_mfma_f32_16x16x32_bf16(wreg[0][kt], bfr, a0, 0,0,0);
            a1 = __builtin_amdgcn_mfma_f32_16x16x32_bf16(wreg[1][kt], bfr, a1, 0,0,0);
            a2 = __builtin_amdgcn_mfma_f32_16x16x32_bf16(wreg[2][kt], bfr, a2, 0,0,0);
            a3 = __builtin_amdgcn_mfma_f32_16x16x32_bf16(wreg[3][kt], bfr, a3, 0,0,0);
        }

        // cell update (C layout: col=l16=batch, row=q*4+r -> unit u0+r)
        float hv0, hv1, hv2, hv3;
        {
            float iv, fv, gv, ov, cn;
            iv=a0[0]+g0[0]; fv=a1[0]+g1[0]; gv=a2[0]+g2[0]; ov=a3[0]+g3[0];
            cn = sigmoidf_(fv)*cc0 + sigmoidf_(iv)*tanh_(gv); cc0=cn; hv0 = sigmoidf_(ov)*tanh_(cn);
            iv=a0[1]+g0[1]; fv=a1[1]+g1[1]; gv=a2[1]+g2[1]; ov=a3[1]+g3[1];
            cn = sigmoidf_(fv)*cc1 + sigmoidf_(iv)*tanh_(gv); cc1=cn; hv1 = sigmoidf_(ov)*tanh_(cn);
            iv=a0[2]+g0[2]; fv=a1[2]+g1[2]; gv=a2[2]+g2[2]; ov=a3[2]+g3[2];
            cn = sigmoidf_(fv)*cc2 + sigmoidf_(iv)*tanh_(gv); cc2=cn; hv2 = sigmoidf_(ov)*tanh_(cn);
            iv=a0[3]+g0[3]; fv=a1[3]+g1[3]; gv=a2[3]+g2[3]; ov=a3[3]+g3[3];
            cn = sigmoidf_(fv)*cc3 + sigmoidf_(iv)*tanh_(gv); cc3=cn; hv3 = sigmoidf_(ov)*tanh_(cn);
        }

        // hseq fp32 (for emissions)
        *(float4*)(hseq + (((size_t)dir*S_ + s)*B_ + b_glob)*H_ + u0) = make_float4(hv0,hv1,hv2,hv3);

        // barrier: all waves finished reading hlds (h(t-1)) before we overwrite own region
        __syncthreads();

        unsigned int p0 = f2bf(hv0) | (f2bf(hv1) << 16);
        unsigned int p1 = f2bf(hv2) | (f2bf(hv3) << 16);
        // own region of LDS for next step
        *(unsigned int*)((char*)hlds + ((size_t)l16*264 + u0    )*2) = p0;
        *(unsigned int*)((char*)hlds + ((size_t)l16*264 + u0 + 2)*2) = p1;
        // publish tagged words for peers (no fence needed: payload+tag in one atomic word)
        unsigned long long w0 = (unsigned long long)p0 | ((unsigned long long)(unsigned)t << 32);
        unsigned long long w1 = (unsigned long long)p1 | ((unsigned long long)(unsigned)t << 32);
        unsigned long long* mybase = ((t & 1) ? grp1 : grp0) + (size_t)jb*512;
        __hip_atomic_store(mybase + (size_t)(ul0  )*16 + l16, w0, __ATOMIC_RELAXED, __HIP_MEMORY_SCOPE_AGENT);
        __hip_atomic_store(mybase + (size_t)(ul0+1)*16 + l16, w1, __ATOMIC_RELAXED, __HIP_MEMORY_SCOPE_AGENT);
    }
}

// ---------------- emissions: em[s][b][nc] = [hf,hr] . lin_w[nc] + lin_b[nc] ----------------
__global__ void k_em(const float* hseq, const float* lw, const float* lb, float* em){
    int idx = blockIdx.x*256 + threadIdx.x;
    if(idx >= S_*B_*NC_) return;
    int nc = idx % NC_;
    int sb = idx / NC_;
    int b = sb % B_, s = sb / B_;
    const float4* hf = (const float4*)(hseq + (((size_t)0*S_ + s)*B_ + b)*H_);
    const float4* hr = (const float4*)(hseq + (((size_t)1*S_ + s)*B_ + b)*H_);
    const float4* w  = (const float4*)(lw + (size_t)nc*2*H_);
    float acc = lb[nc];
    #pragma unroll 8
    for(int k=0;k<H_/4;k++){ float4 a=hf[k], ww=w[k];     acc += a.x*ww.x + a.y*ww.y + a.z*ww.z + a.w*ww.w; }
    #pragma unroll 8
    for(int k=0;k<H_/4;k++){ float4 a=hr[k], ww=w[64+k];  acc += a.x*ww.x + a.y*ww.y + a.z*ww.z + a.w*ww.w; }
    em[idx] = acc;
}

// ---------------- CRF NLL: one block (64 threads) per batch; out += logZ - score ----------------
__global__ void k_crf(const float* em, const int* tag, const void* mask,
                      const float* st, const float* et, const float* tr, float* out){
    __shared__ float trs[NC_*NC_];
    __shared__ float alpha[2][NC_];
    __shared__ float score_sh;
    __shared__ int   len_sh;
    int b = blockIdx.x, tid = threadIdx.x;
    for(int i=tid;i<NC_*NC_;i+=64) trs[i]=tr[i];
    unsigned int first = *(const unsigned int*)mask;
    int ml;  // 0=int32, 1=uint8, 2=float32
    if(first == 1u) ml = 0;
    else if(first == 0x3F800000u) ml = 2;
    else ml = 1;
    __syncthreads();

    float part = 0.f; int cnt = 0;
    for(int s = tid; s < S_; s += 64){
        float mkv;
        {
            int off = b*S_ + s;
            if(ml==0)      mkv = ((const int*)mask)[off] ? 1.f : 0.f;
            else if(ml==1) mkv = ((const unsigned char*)mask)[off] ? 1.f : 0.f;
            else           mkv = ((const float*)mask)[off];
        }
        cnt += (mkv != 0.f) ? 1 : 0;
        if(s == 0){
            int t0 = tag[b*S_];
            part += st[t0] + em[((size_t)0*B_ + b)*NC_ + t0];
        } else {
            int tp = tag[b*S_ + s-1], tc = tag[b*S_ + s];
            part += mkv * (trs[tp*NC_ + tc] + em[((size_t)s*B_ + b)*NC_ + tc]);
        }
    }
    for(int o=32;o>0;o>>=1){ part += __shfl_down(part, o); cnt += __shfl_down(cnt, o); }
    if(tid==0){ len_sh = cnt; score_sh = part; }
    __syncthreads();
    float score = 0.f;
    if(tid == 0){
        int last = len_sh - 1;
        score = score_sh + et[ tag[b*S_ + last] ];
    }

    if(tid < NC_) alpha[0][tid] = st[tid] + em[((size_t)0*B_ + b)*NC_ + tid];
    __syncthreads();
    int cur = 0;
    for(int s=1;s<S_;s++){
        float nv = 0.f;
        if(tid < NC_){
            int j = tid;
            float m = -1e30f;
            #pragma unroll
            for(int i=0;i<NC_;i++){ float v = alpha[cur][i] + trs[i*NC_+j]; m = fmaxf(m, v); }
            float sum = 0.f;
            #pragma unroll
            for(int i=0;i<NC_;i++){ sum += __expf(alpha[cur][i] + trs[i*NC_+j] - m); }
            float nxt = m + __logf(sum) + em[((size_t)s*B_ + b)*NC_ + j];
            float mkv;
            {
                int off = b*S_ + s;
                if(ml==0)      mkv = ((const int*)mask)[off] ? 1.f : 0.f;
                else if(ml==1) mkv = ((const unsigned char*)mask)[off] ? 1.f : 0.f;
                else           mkv = ((const float*)mask)[off];
            }
            nv = (mkv != 0.f) ? nxt : alpha[cur][j];
        }
        __syncthreads();
        if(tid < NC_) alpha[cur^1][tid] = nv;
        __syncthreads();
        cur ^= 1;
    }
    float v = (tid < NC_) ? (alpha[cur][tid] + et[tid]) : -1e30f;
    float m = v;
    for(int o=32;o>0;o>>=1) m = fmaxf(m, __shfl_down(m, o));
    m = __shfl(m, 0);
    float e = (tid < NC_) ? __expf(v - m) : 0.f;
    for(int o=32;o>0;o>>=1) e += __shfl_down(e, o);
    if(tid == 0){
        float logZ = m + __logf(e);
        atomicAdd(out, logZ - score);
    }
}

extern "C" void kernel_launch(void* const* d_in, const int* in_sizes, int n_in,
                              void* d_out, int out_size, void* d_ws, size_t ws_size,
                              hipStream_t stream) {
    const float* word_table = (const float*)d_in[0];
    const float* char_table = (const float*)d_in[1];
    const float* conv_w     = (const float*)d_in[2];
    const float* conv_b     = (const float*)d_in[3];
    const float* w_ih_f     = (const float*)d_in[4];
    const float* w_hh_f     = (const float*)d_in[5];
    const float* b_f        = (const float*)d_in[6];
    const float* w_ih_r     = (const float*)d_in[7];
    const float* w_hh_r     = (const float*)d_in[8];
    const float* b_r        = (const float*)d_in[9];
    const float* lin_w      = (const float*)d_in[10];
    const float* lin_b      = (const float*)d_in[11];
    const float* start_t    = (const float*)d_in[12];
    const float* end_t      = (const float*)d_in[13];
    const float* trans      = (const float*)d_in[14];
    const int*   sent       = (const int*)d_in[15];
    const int*   word       = (const int*)d_in[16];
    const int*   tag        = (const int*)d_in[17];
    const void*  mask       = d_in[18];
    float* out = (float*)d_out;

    float* ws    = (float*)d_ws;
    float* feat  = ws;                                    // 8192*336      = 2,752,512
    float* wpack = feat  + (size_t)B_*S_*KP_;             // 2048*336      =   688,128
    float* gx    = wpack + (size_t)NG_*KP_;               // 2*128*64*1024 = 16,777,216
    float* hseq  = gx    + (size_t)2*S_*B_*G4_;           // 2*128*64*256  =  4,194,304
    float* em    = hseq  + (size_t)2*S_*B_*H_;            // 128*64*25     =    204,800
    unsigned long long* hstage64 = (unsigned long long*)(em + (size_t)S_*B_*NC_);  // 2*16384 u64 = 256 KB

    k_init<<<dim3(1), 64, 0, stream>>>(out);
    k_pack<<<dim3((NG_*KP_+255)/256), 256, 0, stream>>>(w_ih_f, w_ih_r, wpack);
    k_wemb<<<dim3((B_*S_*76+255)/256), 256, 0, stream>>>(word_table, sent, feat);
    k_charconv<<<dim3(B_*S_/8), 256, 0, stream>>>(char_table, word, conv_w, conv_b, feat);
    k_gemm<<<dim3(B_*S_/BM, NG_/BN), 256, 0, stream>>>(feat, wpack, b_f, b_r, gx);
    k_lstm_all<<<dim3(32), 256, 0, stream>>>(w_hh_f, w_hh_r, gx, hseq, hstage64);
    k_em<<<dim3((S_*B_*NC_+255)/256), 256, 0, stream>>>(hseq, lin_w, lin_b, em);
    k_crf<<<dim3(B_), 64, 0, stream>>>(em, tag, mask, start_t, end_t, trans, out);
}